// Round 8
// baseline (277.209 us; speedup 1.0000x reference)
//
#include <hip/hip_runtime.h>
#include <stdint.h>

#define N_NODES 50000
#define N_EDGES 1600000
#define F_IN    264
#define F_HID   48
#define F_CAT   144
#define F_MID   64
#define K_PAD   288   // 264 padded up to multiple of 32
#define K_MLP   160   // 144 padded up to multiple of 32

// bucket-sort CSR build (no global atomics)
#define BSH     6                          // 64 columns per bucket
#define NB      782                        // ceil(50000/64) -> 0..781
#define CHUNK   4096                       // edges per block in bhist/bplace
#define NCHUNK  ((N_EDGES + CHUNK - 1) / CHUNK)   // 391
#define GEMM_BLOCKS ((N_NODES + 127) / 128)       // 391
#define MAXE    16                         // bcsr reg-staging: 4096 edges/bucket cap
                                           // (bucket ~Poisson(2048), 4096 = +45 sigma)

typedef unsigned short u16;
typedef unsigned int   u32;

using short8  = __attribute__((ext_vector_type(8))) short;
using floatx4 = __attribute__((ext_vector_type(4))) float;
using floatx2 = __attribute__((ext_vector_type(2))) float;
using uintx4  = __attribute__((ext_vector_type(4))) u32;

__device__ __forceinline__ float bf2f(u16 u) {
    return __uint_as_float(((u32)u) << 16);
}
__device__ __forceinline__ u16 f2bf(float f) {
    u32 u = __float_as_uint(f);
    u32 r = (u + 0x7fffu + ((u >> 16) & 1u)) >> 16;   // round-nearest-even
    return (u16)r;
}
// dtype-agnostic scalar float load: isbf ? bf16[i] : f32[i]
__device__ __forceinline__ float ldf(const void* p, size_t i, int isbf) {
    return isbf ? bf2f(((const u16*)p)[i]) : ((const float*)p)[i];
}
__device__ __forceinline__ uintx4 s8_to_u4(short8 v) {
    union { short8 s; uintx4 u; } c; c.s = v; return c.u;
}

// ---------- dtype probe: flags[0]=floats-are-bf16, flags[1]=ints-are-int64 ----
__global__ __launch_bounds__(64)
void k_probe(const u16* __restrict__ xu, const int* __restrict__ ei,
             int* __restrict__ flags) {
    int lane = threadIdx.x;
    u16 h = xu[2 * lane];
    u32 E = (h >> 7) & 0xFF;
    int sane = (h == 0) || (E >= 90 && E <= 140);
    unsigned long long m = __ballot(sane);
    int cnt = __popcll(m);
    int z = (lane < 16) ? ei[2 * lane + 1] : 0;
    unsigned long long nz = __ballot(z != 0);
    if (lane == 0) {
        flags[0] = (cnt >= 48) ? 1 : 0;
        flags[1] = (nz == 0ull) ? 1 : 0;
    }
}

__device__ __forceinline__ int ld_row(const int* ei, int e, int is64) {
    return is64 ? ei[2 * (size_t)e] : ei[e];
}
__device__ __forceinline__ int ld_col(const int* ei, int e, int is64) {
    return is64 ? ei[2 * ((size_t)N_EDGES + e)] : ei[(size_t)N_EDGES + e];
}

// ---------- prep: Wt + W1bt bf16 staging + fp32 conversion of small params ---
__global__ __launch_bounds__(256)
void k_prep(const void* __restrict__ WM, const void* __restrict__ WA,
            const void* __restrict__ WS, const void* __restrict__ W1,
            const void* __restrict__ bM, const void* __restrict__ bA,
            const void* __restrict__ b1, const void* __restrict__ W2,
            const void* __restrict__ b2,
            u16* __restrict__ Wt, u16* __restrict__ W1bt,
            float* __restrict__ bMf, float* __restrict__ bAf,
            float* __restrict__ b1f, float* __restrict__ W2f,
            float* __restrict__ b2f, const int* __restrict__ flags) {
    const int isbf = flags[0];
    int t = blockIdx.x * 256 + threadIdx.x;
    if (t < F_CAT * K_PAD) {
        int n = t / K_PAD, k = t - n * K_PAD;
        u16 v = 0;
        if (k < F_IN) {
            const void* W = (n < 48) ? WM : (n < 96) ? WA : WS;
            int nn = (n < 48) ? n : (n < 96) ? n - 48 : n - 96;
            if (isbf) v = ((const u16*)W)[(size_t)k * 48 + nn];
            else      v = f2bf(((const float*)W)[(size_t)k * 48 + nn]);
        }
        Wt[(size_t)n * K_PAD + k] = v;
        return;
    }
    t -= F_CAT * K_PAD;
    if (t < F_MID * K_MLP) {       // W1bt[j][k] = bf16(W1[k][j]), zero-pad k>=144
        int j = t / K_MLP, k = t - j * K_MLP;
        u16 v = 0;
        if (k < F_CAT) {
            if (isbf) v = ((const u16*)W1)[(size_t)k * F_MID + j];
            else      v = f2bf(((const float*)W1)[(size_t)k * F_MID + j]);
        }
        W1bt[t] = v;
        return;
    }
    t -= F_MID * K_MLP;
    if (t < 48)            { bMf[t] = ldf(bM, t, isbf); return; }
    t -= 48;
    if (t < 48)            { bAf[t] = ldf(bA, t, isbf); return; }
    t -= 48;
    if (t < 64)            { b1f[t] = ldf(b1, t, isbf); return; }
    t -= 64;
    if (t < 64)            { W2f[t] = ldf(W2, t, isbf); return; }
    t -= 64;
    if (t < 1)             { b2f[0] = ldf(b2, 0, isbf); return; }
}

// ---------- fused: GEMM blocks [0,GEMM_BLOCKS) + bhist blocks after ----------
// gemm (MFMA-bound) and the bucket histogram (streaming/LDS-bound) are
// independent; co-dispatch lets bhist hide under gemm. Alias-safe now that
// bpair no longer lives in hMB (in-place k_bcsr).
__global__ __launch_bounds__(256)
void k_fgb(const void* __restrict__ x, const u16* __restrict__ Wt,
           u16* __restrict__ hMB, u16* __restrict__ hFull,
           const void* __restrict__ bS,
           const int* __restrict__ ei, u32* __restrict__ bhist,
           const int* __restrict__ flags) {
    const int isbf = flags[0];
    __shared__ u32 hist[NB];
    if (blockIdx.x >= GEMM_BLOCKS) {
        // ---- bhist body ----
        const int is64 = flags[1];
        const int blk = blockIdx.x - GEMM_BLOCKS;
        for (int j = threadIdx.x; j < NB; j += 256) hist[j] = 0;
        __syncthreads();
        int e0 = blk * CHUNK;
        for (int i = 0; i < CHUNK / 256; ++i) {
            int e = e0 + i * 256 + threadIdx.x;
            if (e < N_EDGES) {
                int c = ld_col(ei, e, is64);
                atomicAdd(&hist[(u32)c >> BSH], 1u);      // LDS, non-returning
            }
        }
        __syncthreads();
        for (int j = threadIdx.x; j < NB; j += 256)
            bhist[(size_t)j * NCHUNK + blk] = hist[j];
        return;
    }
    // ---- GEMM body: H[50000 x 144] = x @ [WM|WA|WS] via bf16 MFMA ----------
    const int lane = threadIdx.x & 63;
    const int wave = threadIdx.x >> 6;
    const int mrow = lane & 15;
    const int q    = lane >> 4;
    const int m_base = blockIdx.x * 128 + wave * 32;

    floatx4 acc[2][9];
#pragma unroll
    for (int tt = 0; tt < 2; ++tt)
#pragma unroll
        for (int t = 0; t < 9; ++t) {
            acc[tt][t][0]=0.f; acc[tt][t][1]=0.f; acc[tt][t][2]=0.f; acc[tt][t][3]=0.f;
        }

    for (int k0 = 0; k0 < K_PAD; k0 += 32) {
        int k = k0 + q * 8;
        short8 a[2];
#pragma unroll
        for (int tt = 0; tt < 2; ++tt) {
            int node = m_base + tt * 16 + mrow;
            short8 av = {0,0,0,0,0,0,0,0};
            if (node < N_NODES && k < F_IN) {
                if (isbf) {
                    av = *(const short8*)((const u16*)x + (size_t)node * F_IN + k);
                } else {
                    const float* xf = (const float*)x + (size_t)node * F_IN + k;
                    floatx4 v0 = *(const floatx4*)xf;
                    floatx4 v1 = *(const floatx4*)(xf + 4);
                    av[0]=(short)f2bf(v0[0]); av[1]=(short)f2bf(v0[1]);
                    av[2]=(short)f2bf(v0[2]); av[3]=(short)f2bf(v0[3]);
                    av[4]=(short)f2bf(v1[0]); av[5]=(short)f2bf(v1[1]);
                    av[6]=(short)f2bf(v1[2]); av[7]=(short)f2bf(v1[3]);
                }
            }
            a[tt] = av;
        }
#pragma unroll
        for (int t = 0; t < 9; ++t) {
            short8 b = *(const short8*)(Wt + (size_t)(t * 16 + mrow) * K_PAD + k);
            acc[0][t] = __builtin_amdgcn_mfma_f32_16x16x32_bf16(a[0], b, acc[0][t], 0, 0, 0);
            acc[1][t] = __builtin_amdgcn_mfma_f32_16x16x32_bf16(a[1], b, acc[1][t], 0, 0, 0);
        }
    }
#pragma unroll
    for (int tt = 0; tt < 2; ++tt)
#pragma unroll
    for (int t = 0; t < 9; ++t) {
        int n = t * 16 + mrow;                      // C/D col = lane&15
#pragma unroll
        for (int r = 0; r < 4; ++r) {
            int row = m_base + tt * 16 + q * 4 + r; // C/D row = (lane>>4)*4 + reg
            if (row < N_NODES) {
                float v = acc[tt][t][r];
                if (n < 96) hMB[(size_t)row * 96 + n] = f2bf(v);
                else        hFull[(size_t)row * F_CAT + n] =
                                f2bf(fmaxf(v + ldf(bS, n - 96, isbf), 0.f));
            }
        }
    }
}

// per-bucket exclusive prefix along blocks (in place) + bucket totals.
// WAVE-PER-BUCKET: 64-wide coalesced loads + shfl_up wave scan + carried
// running total.
__global__ __launch_bounds__(256)
void k_bscan1(u32* __restrict__ bhist, u32* __restrict__ bsum) {
    const int wid  = (blockIdx.x * 256 + threadIdx.x) >> 6;   // global wave id
    const int lane = threadIdx.x & 63;
    if (wid >= NB) return;
    u32* row = bhist + (size_t)wid * NCHUNK;
    u32 run = 0;
    for (int i0 = 0; i0 < NCHUNK; i0 += 64) {
        int i = i0 + lane;
        u32 v = (i < NCHUNK) ? row[i] : 0u;
        u32 sc = v;
#pragma unroll
        for (int off = 1; off < 64; off <<= 1) {
            u32 t = (u32)__shfl_up((int)sc, off, 64);
            if (lane >= off) sc += t;
        }
        if (i < NCHUNK) row[i] = run + sc - v;       // exclusive prefix
        run += (u32)__shfl((int)sc, 63, 64);         // carry chunk total
    }
    if (lane == 0) bsum[wid] = run;
}

// exclusive scan of 782 bucket totals -> bucketOffset[0..NB]
__global__ __launch_bounds__(1024)
void k_bscan2(const u32* __restrict__ bsum, u32* __restrict__ boff) {
    __shared__ u32 part[1024];
    int tid = threadIdx.x;
    u32 v = (tid < NB) ? bsum[tid] : 0u;
    part[tid] = v;
    __syncthreads();
    for (int off = 1; off < 1024; off <<= 1) {
        u32 t = (tid >= off) ? part[tid - off] : 0u;
        __syncthreads();
        part[tid] += t;
        __syncthreads();
    }
    if (tid < NB) boff[tid] = part[tid] - v;
    if (tid == NB - 1) boff[NB] = part[tid];
}

// ---------- bucket pass B: place edges into bucket-grouped region ------------
// Target buffer IS csr_pair (bucket-grouped, unsorted within bucket); k_bcsr
// permutes it in place. entry: x = row(16b) | localcol(6b)<<16 ; y = w bits
__global__ __launch_bounds__(256)
void k_bplace(const int* __restrict__ ei, const void* __restrict__ ew,
              const u32* __restrict__ bhist, const u32* __restrict__ boff,
              int2* __restrict__ bpair, const int* __restrict__ flags) {
    const int isbf = flags[0], is64 = flags[1];
    __shared__ u32 cur[NB];
    for (int j = threadIdx.x; j < NB; j += 256)
        cur[j] = boff[j] + bhist[(size_t)j * NCHUNK + blockIdx.x];
    __syncthreads();
    int e0 = blockIdx.x * CHUNK;
    for (int i = 0; i < CHUNK / 256; ++i) {
        int e = e0 + i * 256 + threadIdx.x;
        if (e < N_EDGES) {
            int c = ld_col(ei, e, is64);
            int r = ld_row(ei, e, is64);
            float w = ldf(ew, e, isbf);
            u32 p = atomicAdd(&cur[(u32)c >> BSH], 1u);   // LDS returning
            bpair[p] = make_int2(r | ((c & 63) << 16), __float_as_int(w));
        }
    }
}

// ---------- bucket pass C: IN-PLACE per-bucket CSR finalize + fused deg ------
// One block per bucket. Entries staged in REGISTERS (MAXE*256 = 4096 cap);
// LDS hist + LDS float-atomic deg during the read; s_waitcnt vmcnt(0) +
// barrier guarantees every read landed in VGPRs before any write; scatter
// back sorted into the SAME buffer. Eliminates the separate bpair buffer
// (freeing the hMB alias) and the global deg re-read.
__global__ __launch_bounds__(256)
void k_bcsr(const u32* __restrict__ boff, int* __restrict__ rowptr,
            int2* __restrict__ csr_pair, float* __restrict__ dis) {
    const int b   = blockIdx.x;
    const int tid = threadIdx.x;
    const u32 base = boff[b];
    const u32 n    = boff[b + 1] - base;
    const int c0   = b << BSH;
    __shared__ u32 chist[64], pcur[64];
    __shared__ float dsum[64];
    if (tid < 64) { chist[tid] = 0u; dsum[tid] = 0.f; }
    __syncthreads();
    int2 ev[MAXE];
    u32  lcv[MAXE];
#pragma unroll
    for (int t = 0; t < MAXE; ++t) {
        u32 i = (u32)t * 256u + (u32)tid;
        if (i < n) {
            int2 e2 = csr_pair[base + i];
            ev[t] = e2;
            u32 lc = ((u32)e2.x >> 16) & 63u;
            lcv[t] = lc;
            atomicAdd(&chist[lc], 1u);                     // LDS
            atomicAdd(&dsum[lc], __int_as_float(e2.y));    // LDS float
        } else lcv[t] = 0xFFFFFFFFu;
    }
    asm volatile("s_waitcnt vmcnt(0)" ::: "memory");       // reads -> VGPRs
    __syncthreads();
    if (tid < 64) {                       // first wave: 64-lane exclusive scan
        u32 v = chist[tid];
        u32 sc = v;
        for (int off = 1; off < 64; off <<= 1) {
            u32 t = (u32)__shfl_up((int)sc, off, 64);
            if (tid >= off) sc += t;
        }
        u32 excl = sc - v;
        pcur[tid] = excl;
        int c = c0 + tid;
        if (c <= N_NODES) rowptr[c] = (int)(base + excl);
        if (c < N_NODES)  dis[c] = rsqrtf(1.0f + dsum[tid]);  // +1 = self-loop
    }
    __syncthreads();
#pragma unroll
    for (int t = 0; t < MAXE; ++t) {
        if (lcv[t] != 0xFFFFFFFFu) {
            u32 lr = atomicAdd(&pcur[lcv[t]], 1u);         // LDS returning
            csr_pair[base + lr] = make_int2(ev[t].x & 0xFFFF, ev[t].y);
        }
    }
}

// ---------- aggregation only: one wave per node, writes hFull[.][0..95] ------
// Round-3 best body (4 gathers in flight, VGPR 24, occupancy ~68%).
__global__ __launch_bounds__(256)
void k_agg(const u16* __restrict__ hMB, u16* __restrict__ hFull,
           const int* __restrict__ rowptr, const int2* __restrict__ csr_pair,
           const float* __restrict__ dis,
           const float* __restrict__ bMf, const float* __restrict__ bAf) {
    const int lane = threadIdx.x & 63;
    const int wave = threadIdx.x >> 6;
    const int node = blockIdx.x * 4 + wave;   // grid = 12500*4 == 50000 exactly

    const int g = lane / 12;                  // edge group 0..5 (g==5: lanes 60-63 pad)
    const int s = lane - g * 12;              // feature slot 0..11 (8 bf16 each)
    const bool active = lane < 60;
    const bool isMax = s < 6;                 // slots 0..5: hM max, 6..11: hA sum

    const int start = rowptr[node];
    const int end   = rowptr[node + 1];
    const float dn  = dis[node];
    const float dn2 = dn * dn;                // self-loop norm
    const float padnm = isMax ? dn2 : 0.f;    // pad-gather norm (loop-invariant)

    const u32 s16     = 16u * (u32)s;
    const u32 selfOff = __umul24((u32)node, 192u) + s16;   // self/pad row bytes

    // acc2[p] = features {2p, 2p+1} of this lane's 8-feature slot
    floatx2 acc2[4];
    {
        short8 rv0 = *(const short8*)((const char*)hMB + selfOff);
        uintx4 w4 = s8_to_u4(rv0);
        // max lanes may seed in every group (idempotent under max); SUM lanes
        // seed only in group 0 (else self-loop counted 5x after combine).
        float seed = (isMax || g == 0) ? dn2 : 0.f;
#pragma unroll
        for (int p = 0; p < 4; ++p) {
            acc2[p][0] = seed * __uint_as_float(w4[p] << 16);
            acc2[p][1] = seed * __uint_as_float(w4[p] & 0xffff0000u);
        }
    }

    for (int c0 = start; c0 < end; c0 += 64) {
        int cl = end - c0; if (cl > 64) cl = 64;
        // block-load up to 64 pairs: lane i holds edge c0+i  (clamped, no OOB)
        int li = lane < cl ? lane : cl - 1;
        int2 mp = csr_pair[c0 + li];
        float disr = dis[mp.x];
        float mynm = __int_as_float(mp.y) * disr * dn;     // full norm
        u32 myoff  = __umul24((u32)mp.x, 192u);            // row byte offset

        for (int j = 0; j < cl; j += 20) {
            // stage 1: u32 offsets + weights via shfl (no VMEM dependency)
            u32 offv[4]; float nmv[4];
#pragma unroll
            for (int u = 0; u < 4; ++u) {
                int el = j + 5 * u + g;
                bool valid = active && (el < cl);
                int elc = (el < cl) ? el : 0;
                u32 off  = (u32)__shfl((int)myoff, elc, 64) + s16;
                float nm = __shfl(mynm, elc, 64);
                offv[u] = valid ? off : selfOff;
                nmv[u]  = valid ? nm  : padnm;
            }
            // stage 2: 4 independent gathers in flight
            short8 rv[4];
#pragma unroll
            for (int u = 0; u < 4; ++u)
                rv[u] = *(const short8*)((const char*)hMB + offv[u]);
            // stage 3: packed convert + accumulate
#pragma unroll
            for (int u = 0; u < 4; ++u) {
                uintx4 w4 = s8_to_u4(rv[u]);
                floatx2 nm2; nm2[0] = nmv[u]; nm2[1] = nmv[u];
#pragma unroll
                for (int p = 0; p < 4; ++p) {
                    floatx2 f;
                    f[0] = __uint_as_float(w4[p] << 16);
                    f[1] = __uint_as_float(w4[p] & 0xffff0000u);
                    if (isMax) {
                        floatx2 m = nm2 * f;               // v_pk_mul_f32
                        acc2[p][0] = fmaxf(acc2[p][0], m[0]);
                        acc2[p][1] = fmaxf(acc2[p][1], m[1]);
                    } else {
                        acc2[p] += nm2 * f;                // v_pk_fma_f32
                    }
                }
            }
        }
    }

    // combine the 5 groups into lanes 0..11
#pragma unroll
    for (int gg = 1; gg < 5; ++gg) {
        int src = lane + 12 * gg;
        floatx2 t[4];
#pragma unroll
        for (int p = 0; p < 4; ++p) {
            t[p][0] = __shfl(acc2[p][0], src, 64);
            t[p][1] = __shfl(acc2[p][1], src, 64);
        }
        if (lane < 12) {
            if (isMax) {
#pragma unroll
                for (int p = 0; p < 4; ++p) {
                    acc2[p][0] = fmaxf(acc2[p][0], t[p][0]);
                    acc2[p][1] = fmaxf(acc2[p][1], t[p][1]);
                }
            } else {
#pragma unroll
                for (int p = 0; p < 4; ++p) acc2[p] += t[p];
            }
        }
    }

    if (lane < 12) {
        const float* bp = isMax ? (bMf + 8 * lane) : (bAf + 8 * lane - 48);
        short8 hv;
#pragma unroll
        for (int p = 0; p < 4; ++p) {
            hv[2 * p]     = (short)f2bf(fmaxf(acc2[p][0] + bp[2 * p],     0.f));
            hv[2 * p + 1] = (short)f2bf(fmaxf(acc2[p][1] + bp[2 * p + 1], 0.f));
        }
        *(short8*)(hFull + (size_t)node * F_CAT + 8 * lane) = hv;
    }
}

// ---------- MLP via MFMA: out = (relu(hFull@W1+b1))@W2 + b2 ----------------
// M=50000, K=144 (pad 160), N=64; fused ReLU + W2 dot + b2 in epilogue.
__global__ __launch_bounds__(256)
void k_mlp(const u16* __restrict__ hFull, const u16* __restrict__ W1bt,
           const float* __restrict__ b1f, const float* __restrict__ W2f,
           const float* __restrict__ b2f, void* __restrict__ out,
           const int* __restrict__ flags) {
    const int isbf = flags[0];
    const int lane = threadIdx.x & 63;
    const int wave = threadIdx.x >> 6;
    const int mrow = lane & 15;
    const int q    = lane >> 4;
    const int m_base = blockIdx.x * 64 + wave * 16;
    const int node = m_base + mrow;           // A-operand row

    floatx4 acc[4];
#pragma unroll
    for (int t = 0; t < 4; ++t) { acc[t][0]=0.f; acc[t][1]=0.f; acc[t][2]=0.f; acc[t][3]=0.f; }

    for (int k0 = 0; k0 < K_MLP; k0 += 32) {
        int k = k0 + q * 8;
        short8 a = {0,0,0,0,0,0,0,0};
        if (node < N_NODES && k < F_CAT)
            a = *(const short8*)(hFull + (size_t)node * F_CAT + k);
#pragma unroll
        for (int t = 0; t < 4; ++t) {
            short8 b = *(const short8*)(W1bt + (size_t)(t * 16 + mrow) * K_MLP + k);
            acc[t] = __builtin_amdgcn_mfma_f32_16x16x32_bf16(a, b, acc[t], 0, 0, 0);
        }
    }

    // epilogue: per lane col c=mrow holds mid[n=t*16+c] for rows m=q*4+r
    float pr[4] = {0.f, 0.f, 0.f, 0.f};
#pragma unroll
    for (int t = 0; t < 4; ++t) {
        int n = t * 16 + mrow;
        float b1v = b1f[n], w2v = W2f[n];
#pragma unroll
        for (int r = 0; r < 4; ++r)
            pr[r] += fmaxf(acc[t][r] + b1v, 0.f) * w2v;
    }
    // reduce across the 16 columns (lanes with equal q)
#pragma unroll
    for (int mask = 1; mask < 16; mask <<= 1)
#pragma unroll
        for (int r = 0; r < 4; ++r) pr[r] += __shfl_xor(pr[r], mask, 64);
    if (mrow == 0) {
#pragma unroll
        for (int r = 0; r < 4; ++r) {
            int nd = m_base + q * 4 + r;
            if (nd < N_NODES) {
                float res = pr[r] + b2f[0];
                if (isbf) ((u16*)out)[nd] = f2bf(res);
                else      ((float*)out)[nd] = res;
            }
        }
    }
}

extern "C" void kernel_launch(void* const* d_in, const int* in_sizes, int n_in,
                              void* d_out, int out_size, void* d_ws, size_t ws_size,
                              hipStream_t stream) {
    const void* x  = d_in[0];
    const int*  ei = (const int*)d_in[1];
    const void* ew = d_in[2];
    const void* WM = d_in[3];
    const void* bM = d_in[4];
    const void* WA = d_in[5];
    const void* bA = d_in[6];
    const void* WS = d_in[7];
    const void* bS = d_in[8];
    const void* W1 = d_in[9];
    const void* b1 = d_in[10];
    const void* W2 = d_in[11];
    const void* b2 = d_in[12];

    char* p = (char*)d_ws;
    auto alloc = [&](size_t bytes) -> char* {
        char* r = p; p += (bytes + 255) & ~(size_t)255; return r;
    };
    int*   flags    = (int*)  alloc(16);
    float* dis      = (float*)alloc((size_t)N_NODES * 4);
    int*   rowptr   = (int*)  alloc((size_t)(N_NODES + 1) * 4);
    int2*  csr_pair = (int2*) alloc((size_t)N_EDGES * 8);   // also the bplace target (in-place bcsr)
    u16*   hMB      = (u16*)  alloc((size_t)N_NODES * 96 * 2);
    u16*   hFull    = (u16*)  alloc((size_t)N_NODES * F_CAT * 2);
    u16*   Wt       = (u16*)  alloc((size_t)F_CAT * K_PAD * 2);
    u16*   W1bt    = (u16*)  alloc((size_t)F_MID * K_MLP * 2);
    u32*   bhist    = (u32*)  alloc((size_t)NB * NCHUNK * 4);
    u32*   bsum     = (u32*)  alloc((size_t)NB * 4);
    u32*   boff     = (u32*)  alloc((size_t)(NB + 1) * 4);
    float* bMf      = (float*)alloc(48 * 4);
    float* bAf      = (float*)alloc(48 * 4);
    float* b1f      = (float*)alloc(64 * 4);
    float* W2f      = (float*)alloc(64 * 4);
    float* b2f      = (float*)alloc(4);

    k_probe <<<1, 64, 0, stream>>>((const u16*)x, ei, flags);
    k_prep  <<<(F_CAT * K_PAD + F_MID * K_MLP + 225 + 255) / 256, 256, 0, stream>>>(
                 WM, WA, WS, W1, bM, bA, b1, W2, b2,
                 Wt, W1bt, bMf, bAf, b1f, W2f, b2f, flags);
    k_fgb   <<<GEMM_BLOCKS + NCHUNK, 256, 0, stream>>>(
                 x, Wt, hMB, hFull, bS, ei, bhist, flags);
    k_bscan1<<<(NB * 64 + 255) / 256, 256, 0, stream>>>(bhist, bsum);
    k_bscan2<<<1, 1024, 0, stream>>>(bsum, boff);
    k_bplace<<<NCHUNK, 256, 0, stream>>>(ei, ew, bhist, boff, csr_pair, flags);
    k_bcsr  <<<NB, 256, 0, stream>>>(boff, rowptr, csr_pair, dis);
    k_agg   <<<N_NODES / 4, 256, 0, stream>>>(hMB, hFull, rowptr, csr_pair, dis, bMf, bAf);
    k_mlp   <<<(N_NODES + 63) / 64, 256, 0, stream>>>(hFull, W1bt, b1f, W2f, b2f, d_out, flags);
    (void)in_sizes; (void)n_in; (void)out_size; (void)ws_size;
}

// Round 9
// 260.587 us; speedup vs baseline: 1.0638x; 1.0638x over previous
//
#include <hip/hip_runtime.h>
#include <stdint.h>

#define N_NODES 50000
#define N_EDGES 1600000
#define F_IN    264
#define F_HID   48
#define F_CAT   144
#define F_MID   64
#define K_PAD   288   // 264 padded up to multiple of 32
#define K_MLP   160   // 144 padded up to multiple of 32

// bucket-sort CSR build (no global atomics)
#define BSH     6                          // 64 columns per bucket
#define NB      782                        // ceil(50000/64) -> 0..781
#define NBP     1024                       // NB padded for the block scan
#define CHUNK   4096                       // edges per block in bhist/bplace
#define NCHUNK  ((N_EDGES + CHUNK - 1) / CHUNK)   // 391

typedef unsigned short u16;
typedef unsigned int   u32;

using short8  = __attribute__((ext_vector_type(8))) short;
using floatx4 = __attribute__((ext_vector_type(4))) float;
using floatx2 = __attribute__((ext_vector_type(2))) float;
using uintx4  = __attribute__((ext_vector_type(4))) u32;

__device__ __forceinline__ float bf2f(u16 u) {
    return __uint_as_float(((u32)u) << 16);
}
__device__ __forceinline__ u16 f2bf(float f) {
    u32 u = __float_as_uint(f);
    u32 r = (u + 0x7fffu + ((u >> 16) & 1u)) >> 16;   // round-nearest-even
    return (u16)r;
}
// dtype-agnostic scalar float load: isbf ? bf16[i] : f32[i]
__device__ __forceinline__ float ldf(const void* p, size_t i, int isbf) {
    return isbf ? bf2f(((const u16*)p)[i]) : ((const float*)p)[i];
}
__device__ __forceinline__ uintx4 s8_to_u4(short8 v) {
    union { short8 s; uintx4 u; } c; c.s = v; return c.u;
}

// ---------- dtype probe: flags[0]=floats-are-bf16, flags[1]=ints-are-int64 ----
__global__ __launch_bounds__(64)
void k_probe(const u16* __restrict__ xu, const int* __restrict__ ei,
             int* __restrict__ flags) {
    int lane = threadIdx.x;
    u16 h = xu[2 * lane];
    u32 E = (h >> 7) & 0xFF;
    int sane = (h == 0) || (E >= 90 && E <= 140);
    unsigned long long m = __ballot(sane);
    int cnt = __popcll(m);
    int z = (lane < 16) ? ei[2 * lane + 1] : 0;
    unsigned long long nz = __ballot(z != 0);
    if (lane == 0) {
        flags[0] = (cnt >= 48) ? 1 : 0;
        flags[1] = (nz == 0ull) ? 1 : 0;
    }
}

__device__ __forceinline__ int ld_row(const int* ei, int e, int is64) {
    return is64 ? ei[2 * (size_t)e] : ei[e];
}
__device__ __forceinline__ int ld_col(const int* ei, int e, int is64) {
    return is64 ? ei[2 * ((size_t)N_EDGES + e)] : ei[(size_t)N_EDGES + e];
}

// ---------- prep: Wt + W1bt bf16 staging + fp32 conversion of small params ---
__global__ __launch_bounds__(256)
void k_prep(const void* __restrict__ WM, const void* __restrict__ WA,
            const void* __restrict__ WS, const void* __restrict__ W1,
            const void* __restrict__ bM, const void* __restrict__ bA,
            const void* __restrict__ b1, const void* __restrict__ W2,
            const void* __restrict__ b2,
            u16* __restrict__ Wt, u16* __restrict__ W1bt,
            float* __restrict__ bMf, float* __restrict__ bAf,
            float* __restrict__ b1f, float* __restrict__ W2f,
            float* __restrict__ b2f, const int* __restrict__ flags) {
    const int isbf = flags[0];
    int t = blockIdx.x * 256 + threadIdx.x;
    if (t < F_CAT * K_PAD) {
        int n = t / K_PAD, k = t - n * K_PAD;
        u16 v = 0;
        if (k < F_IN) {
            const void* W = (n < 48) ? WM : (n < 96) ? WA : WS;
            int nn = (n < 48) ? n : (n < 96) ? n - 48 : n - 96;
            if (isbf) v = ((const u16*)W)[(size_t)k * 48 + nn];
            else      v = f2bf(((const float*)W)[(size_t)k * 48 + nn]);
        }
        Wt[(size_t)n * K_PAD + k] = v;
        return;
    }
    t -= F_CAT * K_PAD;
    if (t < F_MID * K_MLP) {       // W1bt[j][k] = bf16(W1[k][j]), zero-pad k>=144
        int j = t / K_MLP, k = t - j * K_MLP;
        u16 v = 0;
        if (k < F_CAT) {
            if (isbf) v = ((const u16*)W1)[(size_t)k * F_MID + j];
            else      v = f2bf(((const float*)W1)[(size_t)k * F_MID + j]);
        }
        W1bt[t] = v;
        return;
    }
    t -= F_MID * K_MLP;
    if (t < 48)            { bMf[t] = ldf(bM, t, isbf); return; }
    t -= 48;
    if (t < 48)            { bAf[t] = ldf(bA, t, isbf); return; }
    t -= 48;
    if (t < 64)            { b1f[t] = ldf(b1, t, isbf); return; }
    t -= 64;
    if (t < 64)            { W2f[t] = ldf(W2, t, isbf); return; }
    t -= 64;
    if (t < 1)             { b2f[0] = ldf(b2, 0, isbf); return; }
}

// ---------- bucket pass A: per-block LDS histogram of 782 buckets ------------
__global__ __launch_bounds__(256)
void k_bhist(const int* __restrict__ ei, u32* __restrict__ bhist,
             const int* __restrict__ flags) {
    const int is64 = flags[1];
    __shared__ u32 hist[NB];
    for (int j = threadIdx.x; j < NB; j += 256) hist[j] = 0;
    __syncthreads();
    int e0 = blockIdx.x * CHUNK;
    for (int i = 0; i < CHUNK / 256; ++i) {
        int e = e0 + i * 256 + threadIdx.x;
        if (e < N_EDGES) {
            int c = ld_col(ei, e, is64);
            atomicAdd(&hist[(u32)c >> BSH], 1u);      // LDS, non-returning
        }
    }
    __syncthreads();
    for (int j = threadIdx.x; j < NB; j += 256)
        bhist[(size_t)j * NCHUNK + blockIdx.x] = hist[j];
}

// per-bucket exclusive prefix along blocks (in place) + bucket totals.
// WAVE-PER-BUCKET: 64-wide coalesced loads + shfl_up wave scan + carry.
__global__ __launch_bounds__(256)
void k_bscan1(u32* __restrict__ bhist, u32* __restrict__ bsum) {
    const int wid  = (blockIdx.x * 256 + threadIdx.x) >> 6;   // global wave id
    const int lane = threadIdx.x & 63;
    if (wid >= NB) return;
    u32* row = bhist + (size_t)wid * NCHUNK;
    u32 run = 0;
    for (int i0 = 0; i0 < NCHUNK; i0 += 64) {
        int i = i0 + lane;
        u32 v = (i < NCHUNK) ? row[i] : 0u;
        u32 sc = v;
#pragma unroll
        for (int off = 1; off < 64; off <<= 1) {
            u32 t = (u32)__shfl_up((int)sc, off, 64);
            if (lane >= off) sc += t;
        }
        if (i < NCHUNK) row[i] = run + sc - v;       // exclusive prefix
        run += (u32)__shfl((int)sc, 63, 64);         // carry chunk total
    }
    if (lane == 0) bsum[wid] = run;
}

// exclusive scan of 782 bucket totals -> bucketOffset[0..NB]
__global__ __launch_bounds__(1024)
void k_bscan2(const u32* __restrict__ bsum, u32* __restrict__ boff) {
    __shared__ u32 part[1024];
    int tid = threadIdx.x;
    u32 v = (tid < NB) ? bsum[tid] : 0u;
    part[tid] = v;
    __syncthreads();
    for (int off = 1; off < 1024; off <<= 1) {
        u32 t = (tid >= off) ? part[tid - off] : 0u;
        __syncthreads();
        part[tid] += t;
        __syncthreads();
    }
    if (tid < NB) boff[tid] = part[tid] - v;
    if (tid == NB - 1) boff[NB] = part[tid];
}

// ---------- bucket pass B: LDS-SORTED scatter into bucket-grouped bpair ------
// The former per-edge random 8B scatter caused write-allocate (~64B read +
// 64B write per cold line, ~200MB HBM). Here: block-local hist -> block scan
// -> LDS-atomic rank -> 32KB staged array sorted by bucket -> linear emit.
// Consecutive threads write consecutive addresses within each (block,bucket)
// run (avg ~5 entries), so most 64B lines are fully covered.
// entry: x = row(16b) | localcol(6b)<<16 | bucket(10b)<<22 ; y = w bits
// (k_bcsr masks bits [21:16] for lc and [15:0] for row -> bucket bits ignored)
__global__ __launch_bounds__(256)
void k_bplace(const int* __restrict__ ei, const void* __restrict__ ew,
              const u32* __restrict__ bhist, const u32* __restrict__ boff,
              int2* __restrict__ bpair, const int* __restrict__ flags) {
    const int isbf = flags[0], is64 = flags[1];
    const int blk = blockIdx.x;
    const int tid = threadIdx.x;
    __shared__ int2 stage[CHUNK];          // 32 KB
    __shared__ u32 lcur[NBP];              // local hist -> rank cursor
    __shared__ u32 lbase[NBP];             // local exclusive prefix
    __shared__ u32 wsum[4];
    for (int j = tid; j < NBP; j += 256) lcur[j] = 0;
    __syncthreads();
    // pass 1: local histogram; cache cols in regs
    const int e0 = blk * CHUNK;
    u32 cv[CHUNK / 256];
#pragma unroll
    for (int i = 0; i < CHUNK / 256; ++i) {
        int e = e0 + i * 256 + tid;
        u32 c = 0xFFFFFFFFu;
        if (e < N_EDGES) {
            c = (u32)ld_col(ei, e, is64);
            atomicAdd(&lcur[c >> BSH], 1u);
        }
        cv[i] = c;
    }
    __syncthreads();
    // block exclusive scan over NBP buckets: 4/thread + wave scans + combine
    {
        u32 a0 = lcur[4 * tid], a1 = lcur[4 * tid + 1];
        u32 a2 = lcur[4 * tid + 2], a3 = lcur[4 * tid + 3];
        u32 s = a0 + a1 + a2 + a3;
        u32 sc = s;
        int lane = tid & 63;
#pragma unroll
        for (int off = 1; off < 64; off <<= 1) {
            u32 t = (u32)__shfl_up((int)sc, off, 64);
            if (lane >= off) sc += t;
        }
        if (lane == 63) wsum[tid >> 6] = sc;
        __syncthreads();
        u32 wbase = 0;
        for (int wv = 0; wv < (tid >> 6); ++wv) wbase += wsum[wv];
        u32 excl = wbase + sc - s;
        lbase[4 * tid]     = excl;
        lbase[4 * tid + 1] = excl + a0;
        lbase[4 * tid + 2] = excl + a0 + a1;
        lbase[4 * tid + 3] = excl + a0 + a1 + a2;
        __syncthreads();                  // all lcur reads done before overwrite
        lcur[4 * tid]     = excl;
        lcur[4 * tid + 1] = excl + a0;
        lcur[4 * tid + 2] = excl + a0 + a1;
        lcur[4 * tid + 3] = excl + a0 + a1 + a2;
    }
    __syncthreads();
    // pass 2: rank + stage sorted by bucket
#pragma unroll
    for (int i = 0; i < CHUNK / 256; ++i) {
        if (cv[i] != 0xFFFFFFFFu) {
            int e = e0 + i * 256 + tid;
            u32 c = cv[i];
            u32 j = c >> BSH;
            int r = ld_row(ei, e, is64);
            float w = ldf(ew, e, isbf);
            u32 slot = atomicAdd(&lcur[j], 1u);    // LDS returning
            stage[slot] = make_int2(r | (int)((c & 63u) << 16) | (int)(j << 22),
                                    __float_as_int(w));
        }
    }
    __syncthreads();
    // pass 3: linear LDS read -> near-coalesced global scatter per bucket run
    int tot = N_EDGES - e0; if (tot > CHUNK) tot = CHUNK;
    for (int i = tid; i < tot; i += 256) {
        int2 e2 = stage[i];
        u32 j = (u32)e2.x >> 22;
        u32 tgt = boff[j] + bhist[(size_t)j * NCHUNK + blk] + ((u32)i - lbase[j]);
        bpair[tgt] = e2;
    }
}

// ---------- bucket pass C: per-bucket CSR finalize + fused deg ---------------
// One block per bucket (64 columns, ~2048 edges): LDS column hist -> wave scan
// -> rowptr; LDS-rank placement into csr_pair; then deg/dis from the fresh
// (L1-hot) segments. All per-edge RMWs are LDS.
__global__ __launch_bounds__(256)
void k_bcsr(const int2* __restrict__ bpair, const u32* __restrict__ boff,
            int* __restrict__ rowptr, int2* __restrict__ csr_pair,
            float* __restrict__ dis) {
    const int b   = blockIdx.x;
    const int tid = threadIdx.x;
    const u32 base = boff[b];
    const u32 n    = boff[b + 1] - base;
    const int c0   = b << BSH;
    __shared__ u32 chist[64], pcur[64], pbeg[64];
    if (tid < 64) chist[tid] = 0;
    __syncthreads();
    for (u32 i = tid; i < n; i += 256)
        atomicAdd(&chist[((u32)bpair[base + i].x >> 16) & 63u], 1u);
    __syncthreads();
    if (tid < 64) {                       // first wave: 64-lane exclusive scan
        u32 v = chist[tid];
        u32 sc = v;
        for (int off = 1; off < 64; off <<= 1) {
            u32 t = (u32)__shfl_up((int)sc, off, 64);
            if (tid >= off) sc += t;
        }
        u32 excl = sc - v;
        pcur[tid] = excl;
        pbeg[tid] = excl;
        int c = c0 + tid;
        if (c <= N_NODES) rowptr[c] = (int)(base + excl);
    }
    __syncthreads();
    for (u32 i = tid; i < n; i += 256) {
        int2 e2 = bpair[base + i];
        u32 lc = ((u32)e2.x >> 16) & 63u;
        u32 lr = atomicAdd(&pcur[lc], 1u);            // LDS returning
        csr_pair[base + lr] = make_int2(e2.x & 0xFFFF, e2.y);
    }
    __syncthreads();
    // fused deg: 4 lanes per column; segments just written -> L1/L2 hot
    int j = tid >> 2, sub = tid & 3;
    int c = c0 + j;
    if (c < N_NODES) {
        u32 s0 = base + pbeg[j], s1 = base + pcur[j];
        float s = 0.f;
        for (u32 i = s0 + sub; i < s1; i += 4)
            s += __int_as_float(csr_pair[i].y);
        s += __shfl_down(s, 2, 4);
        s += __shfl_down(s, 1, 4);
        if (sub == 0) dis[c] = rsqrtf(1.0f + s);      // +1 = self-loop
    }
}

// ---------- GEMM: H[50000 x 144] = x @ [WM|WA|WS] via bf16 MFMA ----------
// hMB[node][96] bf16 (gather table); hFull[node][96..143] = relu(xWS+bS) bf16
__global__ __launch_bounds__(256)
void k_gemm(const void* __restrict__ x, const u16* __restrict__ Wt,
            u16* __restrict__ hMB, u16* __restrict__ hFull,
            const void* __restrict__ bS, const int* __restrict__ flags) {
    const int isbf = flags[0];
    const int lane = threadIdx.x & 63;
    const int wave = threadIdx.x >> 6;
    const int mrow = lane & 15;
    const int q    = lane >> 4;
    const int m_base = blockIdx.x * 128 + wave * 32;

    floatx4 acc[2][9];
#pragma unroll
    for (int tt = 0; tt < 2; ++tt)
#pragma unroll
        for (int t = 0; t < 9; ++t) {
            acc[tt][t][0]=0.f; acc[tt][t][1]=0.f; acc[tt][t][2]=0.f; acc[tt][t][3]=0.f;
        }

    for (int k0 = 0; k0 < K_PAD; k0 += 32) {
        int k = k0 + q * 8;
        short8 a[2];
#pragma unroll
        for (int tt = 0; tt < 2; ++tt) {
            int node = m_base + tt * 16 + mrow;
            short8 av = {0,0,0,0,0,0,0,0};
            if (node < N_NODES && k < F_IN) {
                if (isbf) {
                    av = *(const short8*)((const u16*)x + (size_t)node * F_IN + k);
                } else {
                    const float* xf = (const float*)x + (size_t)node * F_IN + k;
                    floatx4 v0 = *(const floatx4*)xf;
                    floatx4 v1 = *(const floatx4*)(xf + 4);
                    av[0]=(short)f2bf(v0[0]); av[1]=(short)f2bf(v0[1]);
                    av[2]=(short)f2bf(v0[2]); av[3]=(short)f2bf(v0[3]);
                    av[4]=(short)f2bf(v1[0]); av[5]=(short)f2bf(v1[1]);
                    av[6]=(short)f2bf(v1[2]); av[7]=(short)f2bf(v1[3]);
                }
            }
            a[tt] = av;
        }
#pragma unroll
        for (int t = 0; t < 9; ++t) {
            short8 b = *(const short8*)(Wt + (size_t)(t * 16 + mrow) * K_PAD + k);
            acc[0][t] = __builtin_amdgcn_mfma_f32_16x16x32_bf16(a[0], b, acc[0][t], 0, 0, 0);
            acc[1][t] = __builtin_amdgcn_mfma_f32_16x16x32_bf16(a[1], b, acc[1][t], 0, 0, 0);
        }
    }
#pragma unroll
    for (int tt = 0; tt < 2; ++tt)
#pragma unroll
    for (int t = 0; t < 9; ++t) {
        int n = t * 16 + mrow;                      // C/D col = lane&15
#pragma unroll
        for (int r = 0; r < 4; ++r) {
            int row = m_base + tt * 16 + q * 4 + r; // C/D row = (lane>>4)*4 + reg
            if (row < N_NODES) {
                float v = acc[tt][t][r];
                if (n < 96) hMB[(size_t)row * 96 + n] = f2bf(v);
                else        hFull[(size_t)row * F_CAT + n] =
                                f2bf(fmaxf(v + ldf(bS, n - 96, isbf), 0.f));
            }
        }
    }
}

// ---------- aggregation only: one wave per node, writes hFull[.][0..95] ------
// Round-3 best body (4 gathers in flight, VGPR 24, occupancy ~68%).
__global__ __launch_bounds__(256)
void k_agg(const u16* __restrict__ hMB, u16* __restrict__ hFull,
           const int* __restrict__ rowptr, const int2* __restrict__ csr_pair,
           const float* __restrict__ dis,
           const float* __restrict__ bMf, const float* __restrict__ bAf) {
    const int lane = threadIdx.x & 63;
    const int wave = threadIdx.x >> 6;
    const int node = blockIdx.x * 4 + wave;   // grid = 12500*4 == 50000 exactly

    const int g = lane / 12;                  // edge group 0..5 (g==5: lanes 60-63 pad)
    const int s = lane - g * 12;              // feature slot 0..11 (8 bf16 each)
    const bool active = lane < 60;
    const bool isMax = s < 6;                 // slots 0..5: hM max, 6..11: hA sum

    const int start = rowptr[node];
    const int end   = rowptr[node + 1];
    const float dn  = dis[node];
    const float dn2 = dn * dn;                // self-loop norm
    const float padnm = isMax ? dn2 : 0.f;    // pad-gather norm (loop-invariant)

    const u32 s16     = 16u * (u32)s;
    const u32 selfOff = __umul24((u32)node, 192u) + s16;   // self/pad row bytes

    // acc2[p] = features {2p, 2p+1} of this lane's 8-feature slot
    floatx2 acc2[4];
    {
        short8 rv0 = *(const short8*)((const char*)hMB + selfOff);
        uintx4 w4 = s8_to_u4(rv0);
        // max lanes may seed in every group (idempotent under max); SUM lanes
        // seed only in group 0 (else self-loop counted 5x after combine).
        float seed = (isMax || g == 0) ? dn2 : 0.f;
#pragma unroll
        for (int p = 0; p < 4; ++p) {
            acc2[p][0] = seed * __uint_as_float(w4[p] << 16);
            acc2[p][1] = seed * __uint_as_float(w4[p] & 0xffff0000u);
        }
    }

    for (int c0 = start; c0 < end; c0 += 64) {
        int cl = end - c0; if (cl > 64) cl = 64;
        // block-load up to 64 pairs: lane i holds edge c0+i  (clamped, no OOB)
        int li = lane < cl ? lane : cl - 1;
        int2 mp = csr_pair[c0 + li];
        float disr = dis[mp.x];
        float mynm = __int_as_float(mp.y) * disr * dn;     // full norm
        u32 myoff  = __umul24((u32)mp.x, 192u);            // row byte offset

        for (int j = 0; j < cl; j += 20) {
            // stage 1: u32 offsets + weights via shfl (no VMEM dependency)
            u32 offv[4]; float nmv[4];
#pragma unroll
            for (int u = 0; u < 4; ++u) {
                int el = j + 5 * u + g;
                bool valid = active && (el < cl);
                int elc = (el < cl) ? el : 0;
                u32 off  = (u32)__shfl((int)myoff, elc, 64) + s16;
                float nm = __shfl(mynm, elc, 64);
                offv[u] = valid ? off : selfOff;
                nmv[u]  = valid ? nm  : padnm;
            }
            // stage 2: 4 independent gathers in flight
            short8 rv[4];
#pragma unroll
            for (int u = 0; u < 4; ++u)
                rv[u] = *(const short8*)((const char*)hMB + offv[u]);
            // stage 3: packed convert + accumulate
#pragma unroll
            for (int u = 0; u < 4; ++u) {
                uintx4 w4 = s8_to_u4(rv[u]);
                floatx2 nm2; nm2[0] = nmv[u]; nm2[1] = nmv[u];
#pragma unroll
                for (int p = 0; p < 4; ++p) {
                    floatx2 f;
                    f[0] = __uint_as_float(w4[p] << 16);
                    f[1] = __uint_as_float(w4[p] & 0xffff0000u);
                    if (isMax) {
                        floatx2 m = nm2 * f;               // v_pk_mul_f32
                        acc2[p][0] = fmaxf(acc2[p][0], m[0]);
                        acc2[p][1] = fmaxf(acc2[p][1], m[1]);
                    } else {
                        acc2[p] += nm2 * f;                // v_pk_fma_f32
                    }
                }
            }
        }
    }

    // combine the 5 groups into lanes 0..11
#pragma unroll
    for (int gg = 1; gg < 5; ++gg) {
        int src = lane + 12 * gg;
        floatx2 t[4];
#pragma unroll
        for (int p = 0; p < 4; ++p) {
            t[p][0] = __shfl(acc2[p][0], src, 64);
            t[p][1] = __shfl(acc2[p][1], src, 64);
        }
        if (lane < 12) {
            if (isMax) {
#pragma unroll
                for (int p = 0; p < 4; ++p) {
                    acc2[p][0] = fmaxf(acc2[p][0], t[p][0]);
                    acc2[p][1] = fmaxf(acc2[p][1], t[p][1]);
                }
            } else {
#pragma unroll
                for (int p = 0; p < 4; ++p) acc2[p] += t[p];
            }
        }
    }

    if (lane < 12) {
        const float* bp = isMax ? (bMf + 8 * lane) : (bAf + 8 * lane - 48);
        short8 hv;
#pragma unroll
        for (int p = 0; p < 4; ++p) {
            hv[2 * p]     = (short)f2bf(fmaxf(acc2[p][0] + bp[2 * p],     0.f));
            hv[2 * p + 1] = (short)f2bf(fmaxf(acc2[p][1] + bp[2 * p + 1], 0.f));
        }
        *(short8*)(hFull + (size_t)node * F_CAT + 8 * lane) = hv;
    }
}

// ---------- MLP via MFMA: out = (relu(hFull@W1+b1))@W2 + b2 ----------------
// M=50000, K=144 (pad 160), N=64; fused ReLU + W2 dot + b2 in epilogue.
__global__ __launch_bounds__(256)
void k_mlp(const u16* __restrict__ hFull, const u16* __restrict__ W1bt,
           const float* __restrict__ b1f, const float* __restrict__ W2f,
           const float* __restrict__ b2f, void* __restrict__ out,
           const int* __restrict__ flags) {
    const int isbf = flags[0];
    const int lane = threadIdx.x & 63;
    const int wave = threadIdx.x >> 6;
    const int mrow = lane & 15;
    const int q    = lane >> 4;
    const int m_base = blockIdx.x * 64 + wave * 16;
    const int node = m_base + mrow;           // A-operand row

    floatx4 acc[4];
#pragma unroll
    for (int t = 0; t < 4; ++t) { acc[t][0]=0.f; acc[t][1]=0.f; acc[t][2]=0.f; acc[t][3]=0.f; }

    for (int k0 = 0; k0 < K_MLP; k0 += 32) {
        int k = k0 + q * 8;
        short8 a = {0,0,0,0,0,0,0,0};
        if (node < N_NODES && k < F_CAT)
            a = *(const short8*)(hFull + (size_t)node * F_CAT + k);
#pragma unroll
        for (int t = 0; t < 4; ++t) {
            short8 b = *(const short8*)(W1bt + (size_t)(t * 16 + mrow) * K_MLP + k);
            acc[t] = __builtin_amdgcn_mfma_f32_16x16x32_bf16(a, b, acc[t], 0, 0, 0);
        }
    }

    // epilogue: per lane col c=mrow holds mid[n=t*16+c] for rows m=q*4+r
    float pr[4] = {0.f, 0.f, 0.f, 0.f};
#pragma unroll
    for (int t = 0; t < 4; ++t) {
        int n = t * 16 + mrow;
        float b1v = b1f[n], w2v = W2f[n];
#pragma unroll
        for (int r = 0; r < 4; ++r)
            pr[r] += fmaxf(acc[t][r] + b1v, 0.f) * w2v;
    }
    // reduce across the 16 columns (lanes with equal q)
#pragma unroll
    for (int mask = 1; mask < 16; mask <<= 1)
#pragma unroll
        for (int r = 0; r < 4; ++r) pr[r] += __shfl_xor(pr[r], mask, 64);
    if (mrow == 0) {
#pragma unroll
        for (int r = 0; r < 4; ++r) {
            int nd = m_base + q * 4 + r;
            if (nd < N_NODES) {
                float res = pr[r] + b2f[0];
                if (isbf) ((u16*)out)[nd] = f2bf(res);
                else      ((float*)out)[nd] = res;
            }
        }
    }
}

extern "C" void kernel_launch(void* const* d_in, const int* in_sizes, int n_in,
                              void* d_out, int out_size, void* d_ws, size_t ws_size,
                              hipStream_t stream) {
    const void* x  = d_in[0];
    const int*  ei = (const int*)d_in[1];
    const void* ew = d_in[2];
    const void* WM = d_in[3];
    const void* bM = d_in[4];
    const void* WA = d_in[5];
    const void* bA = d_in[6];
    const void* WS = d_in[7];
    const void* bS = d_in[8];
    const void* W1 = d_in[9];
    const void* b1 = d_in[10];
    const void* W2 = d_in[11];
    const void* b2 = d_in[12];

    char* p = (char*)d_ws;
    auto alloc = [&](size_t bytes) -> char* {
        char* r = p; p += (bytes + 255) & ~(size_t)255; return r;
    };
    int*   flags    = (int*)  alloc(16);
    float* dis      = (float*)alloc((size_t)N_NODES * 4);
    int*   rowptr   = (int*)  alloc((size_t)(N_NODES + 1) * 4);
    int2*  csr_pair = (int2*) alloc((size_t)N_EDGES * 8);
    u16*   hMB      = (u16*)  alloc((size_t)N_NODES * 96 * 2);
    u16*   hFull    = (u16*)  alloc((size_t)N_NODES * F_CAT * 2);
    u16*   Wt       = (u16*)  alloc((size_t)F_CAT * K_PAD * 2);
    u16*   W1bt    = (u16*)  alloc((size_t)F_MID * K_MLP * 2);
    u32*   bhist    = (u32*)  alloc((size_t)NB * NCHUNK * 4);
    u32*   bsum     = (u32*)  alloc((size_t)NB * 4);
    u32*   boff     = (u32*)  alloc((size_t)(NB + 1) * 4);
    float* bMf      = (float*)alloc(48 * 4);
    float* bAf      = (float*)alloc(48 * 4);
    float* b1f      = (float*)alloc(64 * 4);
    float* W2f      = (float*)alloc(64 * 4);
    float* b2f      = (float*)alloc(4);
    // bpair (12.8MB) aliases hMB+hFull (24MB): the bucketed edge staging is
    // consumed by k_bcsr strictly before k_gemm writes hMB/hFull.
    int2*  bpair    = (int2*)hMB;

    k_probe <<<1, 64, 0, stream>>>((const u16*)x, ei, flags);
    k_prep  <<<(F_CAT * K_PAD + F_MID * K_MLP + 225 + 255) / 256, 256, 0, stream>>>(
                 WM, WA, WS, W1, bM, bA, b1, W2, b2,
                 Wt, W1bt, bMf, bAf, b1f, W2f, b2f, flags);
    k_bhist <<<NCHUNK, 256, 0, stream>>>(ei, bhist, flags);
    k_bscan1<<<(NB * 64 + 255) / 256, 256, 0, stream>>>(bhist, bsum);
    k_bscan2<<<1, 1024, 0, stream>>>(bsum, boff);
    k_bplace<<<NCHUNK, 256, 0, stream>>>(ei, ew, bhist, boff, bpair, flags);
    k_bcsr  <<<NB, 256, 0, stream>>>(bpair, boff, rowptr, csr_pair, dis);
    k_gemm  <<<(N_NODES + 127) / 128, 256, 0, stream>>>(x, Wt, hMB, hFull, bS, flags);
    k_agg   <<<N_NODES / 4, 256, 0, stream>>>(hMB, hFull, rowptr, csr_pair, dis, bMf, bAf);
    k_mlp   <<<(N_NODES + 63) / 64, 256, 0, stream>>>(hFull, W1bt, b1f, W2f, b2f, d_out, flags);
    (void)in_sizes; (void)n_in; (void)out_size; (void)ws_size;
}